// Round 10
// baseline (166.766 us; speedup 1.0000x reference)
//
#include <hip/hip_runtime.h>

// ---------------- problem constants ----------------
#define DK      768
#define M_ROWS  2048          // 8*256
#define N_ATOM  1001
#define N_BOND  301
#define N_TOT   1603          // 1001 + 2*301
#define N_PADR  1664          // 26 * 64 (padded rows of Wcat)
#define ATOM_ELEMS 2050048    // 2048*1001
#define P_ELEMS    616448     // 2048*301
#define SLAB       77056      // 256*301

typedef __attribute__((ext_vector_type(4))) float f32x4;
typedef __attribute__((ext_vector_type(8))) short bf16x8;

// exact RNE float->bf16
static __device__ __forceinline__ unsigned short f2bf(float f) {
    unsigned u = __float_as_uint(f);
    u += 0x7FFFu + ((u >> 16) & 1u);
    return (unsigned short)(u >> 16);
}

static __device__ __forceinline__ void gload_lds16(const void* g, void* l) {
    __builtin_amdgcn_global_load_lds(
        (const __attribute__((address_space(1))) unsigned*)g,
        (__attribute__((address_space(3))) unsigned*)l, 16, 0, 0);
}

// ---------------- pack: x, Wa, Wb(interleaved W1/W2) -> bf16 ----------------
__global__ __launch_bounds__(256) void pack_bf16(
    const float* __restrict__ x, const float* __restrict__ Wa,
    const float* __restrict__ Wb,
    ushort* __restrict__ xb, ushort* __restrict__ wcat)
{
    const int NX4 = (M_ROWS * DK) / 4;   // 393216
    const int NW4 = (N_PADR * DK) / 4;   // 319488
    int t = blockIdx.x * 256 + threadIdx.x;
    if (t < NX4) {
        float4 v = ((const float4*)x)[t];
        ushort4 o;
        o.x = f2bf(v.x); o.y = f2bf(v.y); o.z = f2bf(v.z); o.w = f2bf(v.w);
        ((ushort4*)xb)[t] = o;
    } else if (t < NX4 + NW4) {
        int u = t - NX4;
        int r = u / 192;                 // 192 float4 per row
        int c = (u - r * 192) * 4;
        float4 v = make_float4(0.f, 0.f, 0.f, 0.f);
        if (r < N_ATOM) {
            v = *(const float4*)(Wa + (size_t)r * DK + c);
        } else if (r < N_TOT) {
            int q = r - N_ATOM;
            v = *(const float4*)(Wb + (size_t)(q >> 1) * (2 * DK) + (q & 1) * DK + c);
        }
        ushort4 o;
        o.x = f2bf(v.x); o.y = f2bf(v.y); o.z = f2bf(v.z); o.w = f2bf(v.w);
        ((ushort4*)wcat)[u] = o;
    }
}

// ---------------- fused bf16 MFMA GEMM (global_load_lds + XOR swizzle) -------
// Identical to R4/R6/R7/R8/R9 (passed, known-good).
__global__ __launch_bounds__(256) void gemm_mfma(
    const ushort* __restrict__ xb, const ushort* __restrict__ wcat,
    const float* __restrict__ ba, const float* __restrict__ bb,
    float* __restrict__ atom, float* __restrict__ p1, float* __restrict__ p2)
{
    __shared__ char As[8192];   // 64 rows x 128B
    __shared__ char Bs[8192];

    const int tid  = threadIdx.x;
    const int lane = tid & 63;
    const int wid  = tid >> 6;     // 4 waves: 2x2
    const int wr   = wid >> 1;
    const int wc   = wid & 1;
    const int m0   = blockIdx.y * 64;
    const int n0   = blockIdx.x * 64;

    f32x4 acc[2][2] = {};

    const int lrow = lane >> 3;                 // 0..7
    const int lcx  = ((lane & 7) ^ lrow) * 8;   // inverse-swizzled k-chunk (elems)

    const ushort* Ag = xb   + (size_t)m0 * DK;
    const ushort* Bg = wcat + (size_t)n0 * DK;

    for (int k0 = 0; k0 < DK; k0 += 64) {
        __syncthreads();   // previous compute done before overwrite
        #pragma unroll
        for (int t = 0; t < 2; ++t) {
            const int s = wid + 4 * t;          // segment 0..7 (1KB each)
            gload_lds16(Ag + (size_t)(s * 8 + lrow) * DK + k0 + lcx, As + s * 1024);
            gload_lds16(Bg + (size_t)(s * 8 + lrow) * DK + k0 + lcx, Bs + s * 1024);
        }
        __syncthreads();   // compiler drains vmcnt(0) before s_barrier
        #pragma unroll
        for (int ks = 0; ks < 2; ++ks) {
            const int kc = ks * 4 + (lane >> 4);
            bf16x8 af[2], bfr[2];
            #pragma unroll
            for (int i = 0; i < 2; ++i) {
                int ra = wr * 32 + i * 16 + (lane & 15);
                af[i]  = *(const bf16x8*)(As + ra * 128 + ((kc ^ (ra & 7)) << 4));
                int rb = wc * 32 + i * 16 + (lane & 15);
                bfr[i] = *(const bf16x8*)(Bs + rb * 128 + ((kc ^ (rb & 7)) << 4));
            }
            #pragma unroll
            for (int i = 0; i < 2; ++i)
                #pragma unroll
                for (int j = 0; j < 2; ++j)
                    acc[i][j] = __builtin_amdgcn_mfma_f32_16x16x32_bf16(
                        af[i], bfr[j], acc[i][j], 0, 0, 0);
        }
    }

    // epilogue: D col = lane&15, row = (lane>>4)*4 + reg  [verified r2/r4/r6-r9]
    #pragma unroll
    for (int i = 0; i < 2; ++i) {
        #pragma unroll
        for (int j = 0; j < 2; ++j) {
            #pragma unroll
            for (int reg = 0; reg < 4; ++reg) {
                int m = m0 + wr * 32 + i * 16 + (lane >> 4) * 4 + reg;
                int n = n0 + wc * 32 + j * 16 + (lane & 15);
                float v = acc[i][j][reg];
                if (n < N_ATOM) {
                    atom[(size_t)m * N_ATOM + n] = v + ba[n];
                } else if (n < N_TOT) {
                    int q = n - N_ATOM, rr = q >> 1;
                    if (q & 1) p2[(size_t)m * N_BOND + rr] = v + bb[rr];
                    else       p1[(size_t)m * N_BOND + rr] = v;
                }
            }
        }
    }
}

// ---------------- bond broadcast: tiled LDS reads + PLAIN float4 stores -----
// Identical to R9 except the store: plain (writeback, L2-aggregated — the
// fill-proven 6.5-6.8 TB/s path) instead of nontemporal. Single-variable A/B.
__global__ __launch_bounds__(256) void bond_bcast(
    const float* __restrict__ p1, const float* __restrict__ p2,
    float* __restrict__ out)
{
    __shared__ float p1s[32 * 344];      // swizzled rows (max idx 337)
    __shared__ float p2s[16 * N_BOND];   // 4816 floats flat
    const int blk = blockIdx.x;          // 1024 = 8b x 8it x 16jt
    const int b   = blk >> 7;
    const int it  = (blk >> 4) & 7;
    const int jt  = blk & 15;
    const int tid = threadIdx.x;

    const float* p1g = p1 + (size_t)(b * 256 + it * 32) * N_BOND;
    for (int t = tid; t < 32 * N_BOND; t += 256) {
        int r = t / N_BOND, n = t - r * N_BOND;
        p1s[r * 344 + n + (n >> 3)] = p1g[t];
    }
    const f32x4* p2g = (const f32x4*)(p2 + (size_t)(b * 256 + jt * 16) * N_BOND);
    for (int k = tid; k < 1204; k += 256) ((f32x4*)p2s)[k] = p2g[k];
    __syncthreads();

    float* dst = out + (size_t)(b * 256 + it * 32) * SLAB + (size_t)(jt * 16) * N_BOND;

    int n = (4 * tid) % 301;
    #pragma unroll
    for (int k = 0; k < 5; ++k) {
        const int f = tid + k * 256;
        if (f < 1204) {
            const f32x4 pv = ((const f32x4*)p2s)[f];
            int n1 = n + 1; if (n1 >= 301) n1 -= 301;
            int n2 = n + 2; if (n2 >= 301) n2 -= 301;
            int n3 = n + 3; if (n3 >= 301) n3 -= 301;
            const int g0 = n + (n >> 3),   g1 = n1 + (n1 >> 3);
            const int g2 = n2 + (n2 >> 3), g3 = n3 + (n3 >> 3);
            for (int i = 0; i < 32; ++i) {
                const float* p1r = p1s + i * 344;
                f32x4 v = pv;
                v.x += p1r[g0]; v.y += p1r[g1]; v.z += p1r[g2]; v.w += p1r[g3];
                *((f32x4*)(dst + (size_t)i * SLAB) + f) = v;
            }
        }
        n += 121; if (n >= 301) n -= 301;
    }
}

// ---------------- launch ----------------
extern "C" void kernel_launch(void* const* d_in, const int* in_sizes, int n_in,
                              void* d_out, int out_size, void* d_ws, size_t ws_size,
                              hipStream_t stream) {
    const float* x  = (const float*)d_in[0];   // (8,256,768)
    const float* Wa = (const float*)d_in[1];   // (1001,768)
    const float* ba = (const float*)d_in[2];   // (1001,)
    const float* Wb = (const float*)d_in[3];   // (301,1536)
    const float* bb = (const float*)d_in[4];   // (301,)

    float* out  = (float*)d_out;
    float* atom = out;                 // 2,050,048 floats
    float* bond = out + ATOM_ELEMS;    // 157,810,688 floats

    // ws layout (16B-aligned sections)
    ushort* xb   = (ushort*)d_ws;                        // 2048*768 bf16
    ushort* wcat = xb + (size_t)M_ROWS * DK;             // 1664*768 bf16
    float*  p1   = (float*)(wcat + (size_t)N_PADR * DK); // 2048*301 f32
    float*  p2   = p1 + P_ELEMS;                         // 2048*301 f32

    pack_bf16<<<dim3(2784), dim3(256), 0, stream>>>(x, Wa, Wb, xb, wcat);

    gemm_mfma<<<dim3(N_PADR / 64, M_ROWS / 64), dim3(256), 0, stream>>>(
        xb, wcat, ba, bb, atom, p1, p2);

    bond_bcast<<<dim3(1024), dim3(256), 0, stream>>>(p1, p2, bond);
}

// Round 11
// 153.703 us; speedup vs baseline: 1.0850x; 1.0850x over previous
//
#include <hip/hip_runtime.h>

// ---------------- problem constants ----------------
#define DK      768
#define M_ROWS  2048          // 8*256
#define N_ATOM  1001
#define N_BOND  301
#define N_TOT   1603          // 1001 + 2*301
#define N_PADR  1664          // 26 * 64 (padded rows of Wcat)
#define ATOM_ELEMS 2050048    // 2048*1001
#define P_ELEMS    616448     // 2048*301
#define BOND_F4    39452672u  // 8*256*256*301 / 4

typedef __attribute__((ext_vector_type(4))) float f32x4;
typedef __attribute__((ext_vector_type(8))) short bf16x8;

// exact RNE float->bf16
static __device__ __forceinline__ unsigned short f2bf(float f) {
    unsigned u = __float_as_uint(f);
    u += 0x7FFFu + ((u >> 16) & 1u);
    return (unsigned short)(u >> 16);
}

static __device__ __forceinline__ void gload_lds16(const void* g, void* l) {
    __builtin_amdgcn_global_load_lds(
        (const __attribute__((address_space(1))) unsigned*)g,
        (__attribute__((address_space(3))) unsigned*)l, 16, 0, 0);
}

// ---------------- pack: x, Wa, Wb(interleaved W1/W2) -> bf16 ----------------
__global__ __launch_bounds__(256) void pack_bf16(
    const float* __restrict__ x, const float* __restrict__ Wa,
    const float* __restrict__ Wb,
    ushort* __restrict__ xb, ushort* __restrict__ wcat)
{
    const int NX4 = (M_ROWS * DK) / 4;   // 393216
    const int NW4 = (N_PADR * DK) / 4;   // 319488
    int t = blockIdx.x * 256 + threadIdx.x;
    if (t < NX4) {
        float4 v = ((const float4*)x)[t];
        ushort4 o;
        o.x = f2bf(v.x); o.y = f2bf(v.y); o.z = f2bf(v.z); o.w = f2bf(v.w);
        ((ushort4*)xb)[t] = o;
    } else if (t < NX4 + NW4) {
        int u = t - NX4;
        int r = u / 192;                 // 192 float4 per row
        int c = (u - r * 192) * 4;
        float4 v = make_float4(0.f, 0.f, 0.f, 0.f);
        if (r < N_ATOM) {
            v = *(const float4*)(Wa + (size_t)r * DK + c);
        } else if (r < N_TOT) {
            int q = r - N_ATOM;
            v = *(const float4*)(Wb + (size_t)(q >> 1) * (2 * DK) + (q & 1) * DK + c);
        }
        ushort4 o;
        o.x = f2bf(v.x); o.y = f2bf(v.y); o.z = f2bf(v.z); o.w = f2bf(v.w);
        ((ushort4*)wcat)[u] = o;
    }
}

// ---------------- fused bf16 MFMA GEMM, 2-phase double-buffered -------------
// C[m,n] = sum_k xb[m,k]*wcat[n,k]; epilogue splits n into atom / p1 / p2(+bb).
// Single isolated change vs R4's gemm: prefetch K-step t+1 into buf^1 before
// computing buf t; one barrier per iter (T3-minimum from the catalog).
__global__ __launch_bounds__(256) void gemm_mfma(
    const ushort* __restrict__ xb, const ushort* __restrict__ wcat,
    const float* __restrict__ ba, const float* __restrict__ bb,
    float* __restrict__ atom, float* __restrict__ p1, float* __restrict__ p2)
{
    __shared__ char As[2][8192];   // 64 rows x 128B each buf
    __shared__ char Bs[2][8192];

    const int tid  = threadIdx.x;
    const int lane = tid & 63;
    const int wid  = tid >> 6;     // 4 waves: 2x2
    const int wr   = wid >> 1;
    const int wc   = wid & 1;
    const int m0   = blockIdx.y * 64;
    const int n0   = blockIdx.x * 64;

    f32x4 acc[2][2] = {};

    const int lrow = lane >> 3;                 // 0..7
    const int lcx  = ((lane & 7) ^ lrow) * 8;   // inverse-swizzled k-chunk (elems)

    const ushort* Ag = xb   + (size_t)m0 * DK;
    const ushort* Bg = wcat + (size_t)n0 * DK;

    auto stage = [&](int buf, int k0) {
        #pragma unroll
        for (int t = 0; t < 2; ++t) {
            const int s = wid + 4 * t;          // segment 0..7 (1KB each)
            gload_lds16(Ag + (size_t)(s * 8 + lrow) * DK + k0 + lcx, &As[buf][s * 1024]);
            gload_lds16(Bg + (size_t)(s * 8 + lrow) * DK + k0 + lcx, &Bs[buf][s * 1024]);
        }
    };
    auto compute = [&](int buf) {
        #pragma unroll
        for (int ks = 0; ks < 2; ++ks) {
            const int kc = ks * 4 + (lane >> 4);
            bf16x8 af[2], bfr[2];
            #pragma unroll
            for (int i = 0; i < 2; ++i) {
                int ra = wr * 32 + i * 16 + (lane & 15);
                af[i]  = *(const bf16x8*)(&As[buf][ra * 128 + ((kc ^ (ra & 7)) << 4)]);
                int rb = wc * 32 + i * 16 + (lane & 15);
                bfr[i] = *(const bf16x8*)(&Bs[buf][rb * 128 + ((kc ^ (rb & 7)) << 4)]);
            }
            #pragma unroll
            for (int i = 0; i < 2; ++i)
                #pragma unroll
                for (int j = 0; j < 2; ++j)
                    acc[i][j] = __builtin_amdgcn_mfma_f32_16x16x32_bf16(
                        af[i], bfr[j], acc[i][j], 0, 0, 0);
        }
    };

    stage(0, 0);
    __syncthreads();                    // buf0 ready (implicit vmcnt(0) drain)
    for (int t = 0; t < 11; ++t) {
        const int cur = t & 1;
        stage(cur ^ 1, (t + 1) * 64);   // next-tile loads fly over this MFMA phase
        compute(cur);
        __syncthreads();
    }
    compute(1);                         // K-step 11

    // epilogue: D col = lane&15, row = (lane>>4)*4 + reg  [verified r2/r4/r6-r10]
    #pragma unroll
    for (int i = 0; i < 2; ++i) {
        #pragma unroll
        for (int j = 0; j < 2; ++j) {
            #pragma unroll
            for (int reg = 0; reg < 4; ++reg) {
                int m = m0 + wr * 32 + i * 16 + (lane >> 4) * 4 + reg;
                int n = n0 + wc * 32 + j * 16 + (lane & 15);
                float v = acc[i][j][reg];
                if (n < N_ATOM) {
                    atom[(size_t)m * N_ATOM + n] = v + ba[n];
                } else if (n < N_TOT) {
                    int q = n - N_ATOM, rr = q >> 1;
                    if (q & 1) p2[(size_t)m * N_BOND + rr] = v + bb[rr];
                    else       p1[(size_t)m * N_BOND + rr] = v;
                }
            }
        }
    }
}

// ---------------- bond broadcast: R4 champion (flat, NT float4) -------------
// out slab(bi) flat f4 index f: elements e=4f..4f+3; out[e] = p2slab[e] + p1row[e%301]
// p2slab identical flat layout -> contiguous f4 L2 reads; write stream globally
// sequential (fill-like) -> best NT locality. n incremental, no divides.
__global__ __launch_bounds__(256) void bond_bcast(
    const float* __restrict__ p1, const float* __restrict__ p2,
    f32x4* __restrict__ out)
{
    __shared__ float p1s[344];          // index swizzle n + (n>>3), max 337
    const int bi  = blockIdx.x;         // 0..2047
    const int b   = bi >> 8;
    const int tid = threadIdx.x;

    for (int n = tid; n < N_BOND; n += 256)
        p1s[n + (n >> 3)] = p1[(size_t)bi * N_BOND + n];
    __syncthreads();

    const f32x4* p2f = (const f32x4*)(p2 + (size_t)(b << 8) * N_BOND);
    f32x4* of = out + (size_t)bi * 19264;   // SLAB/4

    int n = (4 * tid) % 301;
    for (int f = tid; f < 19264; f += 256) {
        f32x4 v = p2f[f];
        int n0 = n;
        int n1 = n + 1; if (n1 >= 301) n1 -= 301;
        int n2 = n + 2; if (n2 >= 301) n2 -= 301;
        int n3 = n + 3; if (n3 >= 301) n3 -= 301;
        v.x += p1s[n0 + (n0 >> 3)];
        v.y += p1s[n1 + (n1 >> 3)];
        v.z += p1s[n2 + (n2 >> 3)];
        v.w += p1s[n3 + (n3 >> 3)];
        __builtin_nontemporal_store(v, &of[f]);
        n += 121; if (n >= 301) n -= 301;
    }
}

// ---------------- launch ----------------
extern "C" void kernel_launch(void* const* d_in, const int* in_sizes, int n_in,
                              void* d_out, int out_size, void* d_ws, size_t ws_size,
                              hipStream_t stream) {
    const float* x  = (const float*)d_in[0];   // (8,256,768)
    const float* Wa = (const float*)d_in[1];   // (1001,768)
    const float* ba = (const float*)d_in[2];   // (1001,)
    const float* Wb = (const float*)d_in[3];   // (301,1536)
    const float* bb = (const float*)d_in[4];   // (301,)

    float* out  = (float*)d_out;
    float* atom = out;                 // 2,050,048 floats
    float* bond = out + ATOM_ELEMS;    // 157,810,688 floats

    // ws layout (16B-aligned sections)
    ushort* xb   = (ushort*)d_ws;                        // 2048*768 bf16
    ushort* wcat = xb + (size_t)M_ROWS * DK;             // 1664*768 bf16
    float*  p1   = (float*)(wcat + (size_t)N_PADR * DK); // 2048*301 f32
    float*  p2   = p1 + P_ELEMS;                         // 2048*301 f32

    pack_bf16<<<dim3(2784), dim3(256), 0, stream>>>(x, Wa, Wb, xb, wcat);

    gemm_mfma<<<dim3(N_PADR / 64, M_ROWS / 64), dim3(256), 0, stream>>>(
        xb, wcat, ba, bb, atom, p1, p2);

    bond_bcast<<<dim3(2048), dim3(256), 0, stream>>>(p1, p2, (f32x4*)bond);
}